// Round 1
// baseline (409.828 us; speedup 1.0000x reference)
//
#include <hip/hip_runtime.h>
#include <cmath>

#define DEV __device__ __forceinline__

constexpr int B_SZ = 16;
constexpr int LSEQ = 256;
constexpr int DM   = 256;   // d_model
constexpr int DI   = 512;   // d_inner
constexpr int NST  = 16;    // d_state
constexpr int RK   = 16;    // dt_rank
constexpr int TLEN = 16;

DEV float silu_f(float x)     { return x / (1.f + __expf(-x)); }
DEV float softplus_f(float x) { return log1pf(__expf(x)); }

// ---------------------------------------------------------------------------
// K1: in-projection (x part only): xi_pre[(b*L+l)*DI + j] = sum_k x[b,k,l]*W_in[j,k]
// M=4096 rows (b,l), N=512 cols j, K=256. 64x64 tiles, K-chunks of 32.
// ---------------------------------------------------------------------------
__global__ __launch_bounds__(256) void k_inproj(const float* __restrict__ x,
                                                const float* __restrict__ W_in,
                                                float* __restrict__ xi_pre) {
    __shared__ float As[32][68];   // [kk][li]
    __shared__ float Ws[32][68];   // [kk][jj]
    const int by = blockIdx.y, bx = blockIdx.x;
    const int row0 = by * 64;
    const int b = row0 >> 8, l0 = row0 & 255;
    const int j0 = bx * 64;
    const int tid = threadIdx.x;
    const int ty = tid >> 4, tx = tid & 15;
    const float* xb = x + (size_t)b * DM * LSEQ;
    float acc[4][4] = {};
    for (int kc = 0; kc < DM; kc += 32) {
        for (int it = 0; it < 8; ++it) {
            int idx = it * 256 + tid;
            int kk = idx >> 6, li = idx & 63;
            As[kk][li] = xb[(kc + kk) * LSEQ + l0 + li];
        }
        for (int it = 0; it < 8; ++it) {
            int idx = it * 256 + tid;
            int jj = idx >> 5, kk = idx & 31;
            Ws[kk][jj] = W_in[(j0 + jj) * DM + kc + kk];
        }
        __syncthreads();
        for (int kk = 0; kk < 32; ++kk) {
            float4 a4 = *(const float4*)&As[kk][ty * 4];
            float4 w4 = *(const float4*)&Ws[kk][tx * 4];
            float av[4] = {a4.x, a4.y, a4.z, a4.w};
            float wv[4] = {w4.x, w4.y, w4.z, w4.w};
            for (int i = 0; i < 4; ++i)
                for (int j = 0; j < 4; ++j) acc[i][j] = fmaf(av[i], wv[j], acc[i][j]);
        }
        __syncthreads();
    }
    for (int i = 0; i < 4; ++i) {
        float4 v = make_float4(acc[i][0], acc[i][1], acc[i][2], acc[i][3]);
        *(float4*)&xi_pre[(size_t)(row0 + ty * 4 + i) * DI + j0 + tx * 4] = v;
    }
}

// ---------------------------------------------------------------------------
// K1b: z at l=255 only: z255[b*DI+j] = sum_k x[b,k,255]*W_in[(DI+j),k]
// ---------------------------------------------------------------------------
__global__ void k_z255(const float* __restrict__ x, const float* __restrict__ W_in,
                       float* __restrict__ z255) {
    const int b = blockIdx.x, tid = threadIdx.x;
    const float* xb = x + (size_t)b * DM * LSEQ;
    for (int jj = tid; jj < DI; jj += 256) {
        const float* wr = W_in + (size_t)(DI + jj) * DM;
        float s = 0.f;
        for (int k = 0; k < DM; ++k) s = fmaf(xb[k * LSEQ + 255], wr[k], s);
        z255[b * DI + jj] = s;
    }
}

// ---------------------------------------------------------------------------
// K2: causal depthwise conv + silu. xi[(b*L+l)*DI+d]
// ---------------------------------------------------------------------------
__global__ __launch_bounds__(512) void k_conv(const float* __restrict__ xi_pre,
                                              const float* __restrict__ conv_w,
                                              const float* __restrict__ conv_b,
                                              float* __restrict__ xi) {
    const int bl = blockIdx.x;       // b*256+l
    const int l = bl & 255;
    const int d = threadIdx.x;
    float s = conv_b[d];
    for (int k = 0; k < 4; ++k) {
        int ll = l - 3 + k;
        if (ll >= 0) s = fmaf(conv_w[d * 4 + k], xi_pre[(size_t)(bl - 3 + k) * DI + d], s);
    }
    xi[(size_t)bl * DI + d] = silu_f(s);
}

// ---------------------------------------------------------------------------
// K3: dtBC[(b*L+l)*48 + r] = sum_k xi[row,k]*W_x[r,k]
// ---------------------------------------------------------------------------
__global__ void k_dtbc(const float* __restrict__ xi, const float* __restrict__ W_x,
                       float* __restrict__ dtBC) {
    const int row = blockIdx.x;
    const int j = threadIdx.x;   // 64 threads, 48 active
    if (j < 48) {
        const float* wr = W_x + (size_t)j * DI;
        const float* xr = xi + (size_t)row * DI;
        float s = 0.f;
        for (int k = 0; k < DI; ++k) s = fmaf(xr[k], wr[k], s);
        dtBC[row * 48 + j] = s;
    }
}

// ---------------------------------------------------------------------------
// K5: chunked scan. blocks = (b,c) b<16,c<8, 512 threads = d.
// For chunk of 32 positions: delta computed inline; emits Q (scan-from-zero)
// and S (sum of delta over chunk) so chunks compose as h = exp(A*S)*h + Q.
// ---------------------------------------------------------------------------
__global__ __launch_bounds__(512) void k_scan_chunk(const float* __restrict__ xi,
                                                    const float* __restrict__ dtBC,
                                                    const float* __restrict__ W_dt,
                                                    const float* __restrict__ b_dt,
                                                    const float* __restrict__ A_log,
                                                    float* __restrict__ Qb,
                                                    float* __restrict__ Sb) {
    const int blk = blockIdx.x;
    const int b = blk >> 3, c = blk & 7;
    const int d = threadIdx.x;
    float Ar[16], Wd[16];
    for (int n = 0; n < 16; ++n) Ar[n] = -__expf(A_log[d * 16 + n]);
    for (int r = 0; r < 16; ++r) Wd[r] = W_dt[d * 16 + r];
    const float bd = b_dt[d];
    float q[16] = {};
    float Ssum = 0.f;
    for (int l = c * 32; l < c * 32 + 32; ++l) {
        const int rl = b * 256 + l;
        const float* dv = dtBC + (size_t)rl * 48;
        float s = bd;
        for (int r = 0; r < 16; ++r) s = fmaf(dv[r], Wd[r], s);
        const float del = softplus_f(s);
        const float u = xi[(size_t)rl * DI + d];
        const float du = del * u;
        Ssum += del;
        for (int n = 0; n < 16; ++n) {
            float dA = __expf(del * Ar[n]);
            q[n] = fmaf(dA, q[n], du * dv[16 + n]);
        }
    }
    float* qo = Qb + ((size_t)blk * DI + d) * 16;
    for (int n = 0; n < 16; ++n) qo[n] = q[n];
    Sb[blk * DI + d] = Ssum;
}

// ---------------------------------------------------------------------------
// K6: compose 8 chunks -> h at position 255; y255, gate -> g0; store h_state.
// ---------------------------------------------------------------------------
__global__ __launch_bounds__(512) void k_compose(const float* __restrict__ Qb,
                                                 const float* __restrict__ Sb,
                                                 const float* __restrict__ dtBC,
                                                 const float* __restrict__ xi,
                                                 const float* __restrict__ z255,
                                                 const float* __restrict__ A_log,
                                                 const float* __restrict__ Dp,
                                                 float* __restrict__ h_state,
                                                 float* __restrict__ gbuf) {
    const int b = blockIdx.x;
    const int d = threadIdx.x;
    float Ar[16];
    for (int n = 0; n < 16; ++n) Ar[n] = -__expf(A_log[d * 16 + n]);
    float h[16] = {};
    for (int c = 0; c < 8; ++c) {
        const int blk = b * 8 + c;
        const float S = Sb[blk * DI + d];
        const float* qv = Qb + ((size_t)blk * DI + d) * 16;
        for (int n = 0; n < 16; ++n) {
            float P = __expf(S * Ar[n]);
            h[n] = fmaf(P, h[n], qv[n]);
        }
    }
    const float* Cv = dtBC + (size_t)(b * 256 + 255) * 48 + 32;
    float y = 0.f;
    for (int n = 0; n < 16; ++n) y = fmaf(h[n], Cv[n], y);
    const float u = xi[(size_t)(b * 256 + 255) * DI + d];
    y = fmaf(u, Dp[d], y);
    gbuf[b * DI + d] = y * silu_f(z255[b * DI + d]);
    float* ho = h_state + ((size_t)(b * DI + d)) * 16;
    for (int n = 0; n < 16; ++n) ho[n] = h[n];
}

// ---------------------------------------------------------------------------
// K7: persistent generation kernel. 128 blocks: b = bid&15, p = bid>>4
// (8 blocks per batch element, 64-wide d-slices). 2 group barriers per step.
// ---------------------------------------------------------------------------
DEV void group_barrier(unsigned* flag, unsigned target) {
    __syncthreads();
    if (threadIdx.x == 0) {
        __hip_atomic_fetch_add(flag, 1u, __ATOMIC_ACQ_REL, __HIP_MEMORY_SCOPE_AGENT);
        while (__hip_atomic_load(flag, __ATOMIC_ACQUIRE, __HIP_MEMORY_SCOPE_AGENT) < target) {
            __builtin_amdgcn_s_sleep(2);
        }
    }
    __syncthreads();
}

__global__ __launch_bounds__(256) void k_gen(
    const float* __restrict__ W_in, const float* __restrict__ conv_w,
    const float* __restrict__ conv_b, const float* __restrict__ W_x,
    const float* __restrict__ W_dt, const float* __restrict__ b_dt,
    const float* __restrict__ A_log, const float* __restrict__ Dp,
    const float* __restrict__ W_out, const float* __restrict__ xi_pre,
    const float* __restrict__ h_state, const float* __restrict__ gbuf0,
    float* __restrict__ o_part, float* __restrict__ dt_part,
    unsigned* __restrict__ bar, float* __restrict__ out) {
    const int bid = blockIdx.x;
    const int b = bid & 15;
    const int p = bid >> 4;
    const int d0 = p * 64;
    const int tid = threadIdx.x;

    __shared__ float gs[64];       // gated-y slice
    __shared__ float os[256];      // reduced o
    __shared__ float hist[3][64];  // conv history (pre-conv in-proj values)
    __shared__ float xin[64];      // post conv+silu slice
    __shared__ float zs[64];       // z slice (raw)
    __shared__ float dtbc[48];     // reduced dt/B/C
    __shared__ float red[256];     // partial scratch

    const int dl = tid >> 2, nq = tid & 3;
    const int dg = d0 + dl;

    float h[4], Ar[4];
    {
        const float* hs = h_state + ((size_t)(b * DI + dg)) * 16 + nq * 4;
        for (int j = 0; j < 4; ++j) h[j] = hs[j];
        for (int j = 0; j < 4; ++j) Ar[j] = -__expf(A_log[dg * 16 + nq * 4 + j]);
    }
    if (tid < 64) {
        gs[tid] = gbuf0[b * DI + d0 + tid];
        for (int k = 0; k < 3; ++k)
            hist[k][tid] = xi_pre[(size_t)(b * 256 + 253 + k) * DI + d0 + tid];
    }
    __syncthreads();

    unsigned* mybar = bar + b;
    unsigned nb = 0;

    for (int t = 0; t < TLEN; ++t) {
        // ---- P1: o partial over this d-slice
        {
            const float* wr = W_out + (size_t)tid * DI + d0;
            float s = 0.f;
            for (int dd = 0; dd < 64; ++dd) s = fmaf(wr[dd], gs[dd], s);
            __hip_atomic_store(&o_part[(b * 8 + p) * 256 + tid], s,
                               __ATOMIC_RELAXED, __HIP_MEMORY_SCOPE_AGENT);
        }
        ++nb; group_barrier(mybar, 8u * nb);

        // ---- P2: reduce o; write output token
        {
            float s = 0.f;
            for (int pp = 0; pp < 8; ++pp)
                s += __hip_atomic_load(&o_part[(b * 8 + pp) * 256 + tid],
                                       __ATOMIC_RELAXED, __HIP_MEMORY_SCOPE_AGENT);
            os[tid] = s;
            if (p == 0) out[(b * 256 + tid) * TLEN + t] = s;
        }
        __syncthreads();
        if (t == TLEN - 1) return;

        // in-proj for the new token: 128 dots (64 x-part + 64 z-part), K=256
        {
            const int jj = tid >> 1, half = tid & 1;
            const int jglob = (jj < 64) ? (d0 + jj) : (DI + d0 + (jj - 64));
            const float* wr = W_in + (size_t)jglob * DM + half * 128;
            const float* ov = os + half * 128;
            float s = 0.f;
            for (int k = 0; k < 128; ++k) s = fmaf(wr[k], ov[k], s);
            red[tid] = s;
        }
        __syncthreads();
        if (tid < 128) {
            const int jj = tid;
            float v = red[2 * jj] + red[2 * jj + 1];
            if (jj < 64) {
                const int d = d0 + jj;
                float xc = conv_b[d];
                xc = fmaf(conv_w[d * 4 + 0], hist[t % 3][jj], xc);
                xc = fmaf(conv_w[d * 4 + 1], hist[(t + 1) % 3][jj], xc);
                xc = fmaf(conv_w[d * 4 + 2], hist[(t + 2) % 3][jj], xc);
                xc = fmaf(conv_w[d * 4 + 3], v, xc);
                hist[t % 3][jj] = v;   // becomes newest
                xin[jj] = silu_f(xc);
            } else {
                zs[jj - 64] = v;
            }
        }
        __syncthreads();
        // dtBC partials over this d-slice: 48 dots, K=64 split 4 ways
        if (tid < 192) {
            const int r = tid >> 2, q4 = tid & 3;
            const float* wr = W_x + (size_t)r * DI + d0 + q4 * 16;
            const float* xv = xin + q4 * 16;
            float s = 0.f;
            for (int k = 0; k < 16; ++k) s = fmaf(wr[k], xv[k], s);
            red[tid] = s;
        }
        __syncthreads();
        if (tid < 48) {
            float v = red[4 * tid] + red[4 * tid + 1] + red[4 * tid + 2] + red[4 * tid + 3];
            __hip_atomic_store(&dt_part[(b * 8 + p) * 48 + tid], v,
                               __ATOMIC_RELAXED, __HIP_MEMORY_SCOPE_AGENT);
        }
        ++nb; group_barrier(mybar, 8u * nb);

        // ---- P3: reduce dtBC; delta; scan step; gate -> gs
        if (tid < 48) {
            float s = 0.f;
            for (int pp = 0; pp < 8; ++pp)
                s += __hip_atomic_load(&dt_part[(b * 8 + pp) * 48 + tid],
                                       __ATOMIC_RELAXED, __HIP_MEMORY_SCOPE_AGENT);
            dtbc[tid] = s;
        }
        __syncthreads();
        {
            float dt_l = b_dt[dg];
            for (int r = 0; r < 16; ++r) dt_l = fmaf(dtbc[r], W_dt[dg * 16 + r], dt_l);
            const float del = softplus_f(dt_l);
            const float u = xin[dl];
            const float du = del * u;
            float y = 0.f;
            for (int j = 0; j < 4; ++j) {
                const int n = nq * 4 + j;
                float dA = __expf(del * Ar[j]);
                h[j] = fmaf(dA, h[j], du * dtbc[16 + n]);
                y = fmaf(h[j], dtbc[32 + n], y);
            }
            y += __shfl_xor(y, 1);
            y += __shfl_xor(y, 2);
            if (nq == 0) {
                float yt = fmaf(u, Dp[dg], y);
                gs[dl] = yt * silu_f(zs[dl]);
            }
        }
        __syncthreads();
    }
}

// ---------------------------------------------------------------------------
extern "C" void kernel_launch(void* const* d_in, const int* in_sizes, int n_in,
                              void* d_out, int out_size, void* d_ws, size_t ws_size,
                              hipStream_t stream) {
    const float* x      = (const float*)d_in[0];
    const float* W_in   = (const float*)d_in[1];
    const float* conv_w = (const float*)d_in[2];
    const float* conv_b = (const float*)d_in[3];
    const float* W_x    = (const float*)d_in[4];
    const float* W_dt   = (const float*)d_in[5];
    const float* b_dt   = (const float*)d_in[6];
    const float* A_log  = (const float*)d_in[7];
    const float* Dp     = (const float*)d_in[8];
    const float* W_out  = (const float*)d_in[9];
    float* out = (float*)d_out;

    float* base = (float*)d_ws;
    size_t off = 0;
    auto alloc = [&](size_t n) { float* pp = base + off; off += (n + 15) & ~(size_t)15; return pp; };
    unsigned* bar   = (unsigned*)alloc(64);
    float* o_part   = alloc(16 * 8 * 256);
    float* dt_part  = alloc(16 * 8 * 48);
    float* gbuf     = alloc(16 * 512);
    float* h_state  = alloc((size_t)16 * 512 * 16);
    float* z255     = alloc(16 * 512);
    float* dtBC     = alloc((size_t)4096 * 48);
    float* Sb       = alloc((size_t)128 * 512);
    float* Qb       = alloc((size_t)128 * 512 * 16);
    float* xi_pre   = alloc((size_t)4096 * 512);
    float* xi       = alloc((size_t)4096 * 512);

    hipMemsetAsync(bar, 0, 256, stream);
    hipLaunchKernelGGL(k_inproj, dim3(8, 64), dim3(256), 0, stream, x, W_in, xi_pre);
    hipLaunchKernelGGL(k_z255, dim3(16), dim3(256), 0, stream, x, W_in, z255);
    hipLaunchKernelGGL(k_conv, dim3(4096), dim3(512), 0, stream, xi_pre, conv_w, conv_b, xi);
    hipLaunchKernelGGL(k_dtbc, dim3(4096), dim3(64), 0, stream, xi, W_x, dtBC);
    hipLaunchKernelGGL(k_scan_chunk, dim3(128), dim3(512), 0, stream,
                       xi, dtBC, W_dt, b_dt, A_log, Qb, Sb);
    hipLaunchKernelGGL(k_compose, dim3(16), dim3(512), 0, stream,
                       Qb, Sb, dtBC, xi, z255, A_log, Dp, h_state, gbuf);
    hipLaunchKernelGGL(k_gen, dim3(128), dim3(256), 0, stream,
                       W_in, conv_w, conv_b, W_x, W_dt, b_dt, A_log, Dp, W_out,
                       xi_pre, h_state, gbuf, o_part, dt_part, bar, out);
}